// Round 1
// baseline (826.671 us; speedup 1.0000x reference)
//
#include <hip/hip_runtime.h>

// Problem constants (B=4, C=64, H=W=128, O=64, K=3, stride=1, pad=1, dil=1)
#define B_   4
#define C_   64
#define O_   64
#define H_   128
#define W_   128
#define HW_  (H_ * W_)
#define KK_  9
#define M_   18   // 2*KK offset channels

// ---------------------------------------------------------------------------
// Kernel A: repack weight [O][C][3][3] -> wt[k][c][o]  (coalesced over o)
// ---------------------------------------------------------------------------
__global__ void repack_weight(const float* __restrict__ w, float* __restrict__ wt) {
    int i = blockIdx.x * blockDim.x + threadIdx.x;
    if (i >= O_ * C_ * KK_) return;
    int o = i / (C_ * KK_);
    int r = i % (C_ * KK_);
    int c = r / KK_;
    int k = r % KK_;
    wt[(k * C_ + c) * O_ + o] = w[i];
}

// ---------------------------------------------------------------------------
// Kernel B: offset conv. One thread per output pixel, all 18 offset channels
// accumulated in registers. Weight addresses are threadIdx-independent ->
// scalar (s_load) path; x loads are coalesced over wo.
// ---------------------------------------------------------------------------
__global__ __launch_bounds__(128) void offset_conv(
        const float* __restrict__ x, const float* __restrict__ ow,
        const float* __restrict__ ob, float* __restrict__ off) {
    const int wo = threadIdx.x;          // 0..127
    const int ho = blockIdx.x & (H_ - 1);
    const int b  = blockIdx.x >> 7;

    float acc[M_];
    #pragma unroll
    for (int m = 0; m < M_; ++m) acc[m] = ob[m];

    const float* xb = x + (size_t)b * C_ * HW_;
    for (int c = 0; c < C_; ++c) {
        const float* xc = xb + c * HW_;
        #pragma unroll
        for (int ky = 0; ky < 3; ++ky) {
            int y = ho - 1 + ky;
            bool yv = ((unsigned)y < (unsigned)H_);
            #pragma unroll
            for (int kx = 0; kx < 3; ++kx) {
                int xcd = wo - 1 + kx;
                float xv = (yv && (unsigned)xcd < (unsigned)W_) ? xc[y * W_ + xcd] : 0.f;
                // weight index uniform across the wave -> scalar loads
                #pragma unroll
                for (int m = 0; m < M_; ++m)
                    acc[m] += xv * ow[(m * C_ + c) * KK_ + ky * 3 + kx];
            }
        }
    }
    int base = ((b * M_) * H_ + ho) * W_ + wo;
    #pragma unroll
    for (int m = 0; m < M_; ++m)
        off[base + m * HW_] = acc[m];
}

// ---------------------------------------------------------------------------
// Kernel C: deformable conv. One wave (64 lanes) per output pixel.
//   Phase 1 (lane = c): bilinear-sample 9 taps x 64 channels -> LDS (576 f32)
//   Phase 2 (lane = o): out[o] = bias[o] + sum_s val[s] * wt[s][o]
// ---------------------------------------------------------------------------
__global__ __launch_bounds__(256) void deform(
        const float* __restrict__ x, const float* __restrict__ off,
        const float* __restrict__ wt, const float* __restrict__ bias,
        float* __restrict__ out) {
    __shared__ float vals[4][KK_ * C_];   // 4 waves x 576 floats = 9216 B

    const int wave = threadIdx.x >> 6;
    const int lane = threadIdx.x & 63;
    const int pix  = blockIdx.x * 4 + wave;
    const int wo = pix & (W_ - 1);
    const int ho = (pix >> 7) & (H_ - 1);
    const int b  = pix >> 14;

    const float* xb = x + (size_t)(b * C_ + lane) * HW_;  // channel plane c=lane

    #pragma unroll
    for (int k = 0; k < KK_; ++k) {
        const int ky = k / 3, kx = k % 3;
        // per-tap offsets: wave-uniform loads (broadcast)
        float offy = off[((b * M_ + 2 * k    ) * H_ + ho) * W_ + wo];
        float offx = off[((b * M_ + 2 * k + 1) * H_ + ho) * W_ + wo];
        float py = (float)(ho - 1 + ky) + offy;
        float px = (float)(wo - 1 + kx) + offx;
        float fy = floorf(py), fx = floorf(px);
        int   y0 = (int)fy,    x0 = (int)fx;
        float wy1 = py - fy,   wx1 = px - fx;
        float wy0 = 1.f - wy1, wx0 = 1.f - wx1;
        int   y1 = y0 + 1,     x1 = x0 + 1;
        bool y0v = ((unsigned)y0 < (unsigned)H_);
        bool y1v = ((unsigned)y1 < (unsigned)H_);
        bool x0v = ((unsigned)x0 < (unsigned)W_);
        bool x1v = ((unsigned)x1 < (unsigned)W_);
        float v00 = (y0v && x0v) ? xb[y0 * W_ + x0] : 0.f;
        float v01 = (y0v && x1v) ? xb[y0 * W_ + x1] : 0.f;
        float v10 = (y1v && x0v) ? xb[y1 * W_ + x0] : 0.f;
        float v11 = (y1v && x1v) ? xb[y1 * W_ + x1] : 0.f;
        vals[wave][k * C_ + lane] =
            wy0 * (wx0 * v00 + wx1 * v01) + wy1 * (wx0 * v10 + wx1 * v11);
    }
    __syncthreads();

    float acc = 0.f;
    const float* vp = vals[wave];
    #pragma unroll 8
    for (int s = 0; s < KK_ * C_; ++s)
        acc += vp[s] * wt[s * O_ + lane];          // vp[s] broadcast; wt coalesced

    out[((size_t)(b * O_ + lane) * H_ + ho) * W_ + wo] = acc + bias[lane];
}

// ---------------------------------------------------------------------------
extern "C" void kernel_launch(void* const* d_in, const int* in_sizes, int n_in,
                              void* d_out, int out_size, void* d_ws, size_t ws_size,
                              hipStream_t stream) {
    const float* x    = (const float*)d_in[0];  // [4,64,128,128]
    const float* ow   = (const float*)d_in[1];  // [18,64,3,3]
    const float* ob   = (const float*)d_in[2];  // [18]
    const float* w    = (const float*)d_in[3];  // [64,64,3,3]
    const float* bias = (const float*)d_in[4];  // [64]
    float* out = (float*)d_out;                 // [4,64,128,128]

    float* off = (float*)d_ws;                  // [4,18,128,128] = 1179648 f
    float* wt  = off + (size_t)B_ * M_ * HW_;   // [9,64,64]      =   36864 f

    repack_weight<<<(O_ * C_ * KK_ + 255) / 256, 256, 0, stream>>>(w, wt);
    offset_conv<<<B_ * H_, 128, 0, stream>>>(x, ow, ob, off);
    deform<<<B_ * HW_ / 4, 256, 0, stream>>>(x, off, wt, bias, out);
}

// Round 2
// 294.884 us; speedup vs baseline: 2.8034x; 2.8034x over previous
//
#include <hip/hip_runtime.h>

// Problem constants (B=4, C=64, H=W=128, O=64, K=3, stride=1, pad=1, dil=1)
#define B_   4
#define C_   64
#define O_   64
#define H_   128
#define W_   128
#define HW_  (H_ * W_)
#define KK_  9
#define M_   18          // 2*KK offset channels
#define OWT_STRIDE 20    // 18 offset-conv weights padded to 20 for float4 loads

// ---------------------------------------------------------------------------
// Repack both weight tensors into layouts whose MAC-phase loads are
// wave-uniform (scalar s_load) with o / m contiguous:
//   wt [s][o]   s = c*9 + (ky*3+kx), o contiguous          (576*64 floats)
//   owt[s][m]   same s, m contiguous, stride padded to 20  (576*20 floats)
// ---------------------------------------------------------------------------
__global__ void repack(const float* __restrict__ w, const float* __restrict__ ow,
                       float* __restrict__ wt, float* __restrict__ owt) {
    int i = blockIdx.x * blockDim.x + threadIdx.x;
    if (i < 576 * O_) {
        int s = i >> 6, o = i & 63;
        wt[i] = w[o * 576 + s];                 // wt[s*64+o] = w[o][s]
    }
    if (i < 576 * M_) {
        int s = i / M_, m = i % M_;
        owt[s * OWT_STRIDE + m] = ow[m * 576 + s];   // owt[s*20+m] = ow[m][s]
    }
}

// ---------------------------------------------------------------------------
// Fused deformable conv. One block = 64-pixel row segment (b, ho, wo_base).
// lane = pixel (consecutive wo) in ALL phases -> coalesced/near-coalesced VMEM.
//   Phase A: offset conv. wave w covers channels [16w,16w+16); partials
//            LDS-reduced into offs[18][64] (+offset bias).
//   Phase B: 4 chunks of 16 channels:
//     B1 sampling: wave w samples channels [4w,4w+4) x 9 taps -> vals[s][p]
//        (geometry per tap computed once, validity folded into corner weights)
//     B2 MAC: all waves iterate 144 s; vals[s][lane] stride-1 LDS read,
//        wt[s][o-slice] wave-uniform float4 scalar loads, acc[16] registers.
// ---------------------------------------------------------------------------
__global__ __launch_bounds__(256) void dcn_fused(
        const float* __restrict__ x, const float* __restrict__ owt,
        const float* __restrict__ ob, const float* __restrict__ wt,
        const float* __restrict__ bias, float* __restrict__ out) {
    __shared__ union {
        float part[4][M_ * 64];   // phase-A partials (18432 B)
        float vals[144 * 64];     // phase-B chunk buffer (36864 B)
    } u;
    __shared__ float offs[M_ * 64];  // 4608 B

    const int tid   = threadIdx.x;
    const int lane  = tid & 63;
    const int wslot = __builtin_amdgcn_readfirstlane(tid >> 6);
    const int wo_base = (blockIdx.x & 1) << 6;
    const int ho = (blockIdx.x >> 1) & (H_ - 1);
    const int b  = blockIdx.x >> 8;
    const int wo = wo_base + lane;
    const float* xb = x + (size_t)b * C_ * HW_;

    // ---------------- Phase A: offset conv ----------------
    float oacc[M_];
    #pragma unroll
    for (int m = 0; m < M_; ++m) oacc[m] = 0.f;

    for (int cl = 0; cl < 16; ++cl) {
        const int c = wslot * 16 + cl;
        const float* xc = xb + c * HW_;
        #pragma unroll
        for (int ky = 0; ky < 3; ++ky) {
            const int y = ho - 1 + ky;
            const bool yv = (unsigned)y < (unsigned)H_;
            #pragma unroll
            for (int kx = 0; kx < 3; ++kx) {
                const int col = wo - 1 + kx;
                const float xv =
                    (yv && (unsigned)col < (unsigned)W_) ? xc[y * W_ + col] : 0.f;
                const float* wr = owt + (c * 9 + ky * 3 + kx) * OWT_STRIDE;
                const float4* w4 = (const float4*)wr;      // wave-uniform -> s_load
                const float4 wa = w4[0], wb = w4[1], wc = w4[2], wd = w4[3];
                const float we = wr[16], wf = wr[17];
                oacc[0]  += xv * wa.x; oacc[1]  += xv * wa.y;
                oacc[2]  += xv * wa.z; oacc[3]  += xv * wa.w;
                oacc[4]  += xv * wb.x; oacc[5]  += xv * wb.y;
                oacc[6]  += xv * wb.z; oacc[7]  += xv * wb.w;
                oacc[8]  += xv * wc.x; oacc[9]  += xv * wc.y;
                oacc[10] += xv * wc.z; oacc[11] += xv * wc.w;
                oacc[12] += xv * wd.x; oacc[13] += xv * wd.y;
                oacc[14] += xv * wd.z; oacc[15] += xv * wd.w;
                oacc[16] += xv * we;   oacc[17] += xv * wf;
            }
        }
    }
    #pragma unroll
    for (int m = 0; m < M_; ++m) u.part[wslot][m * 64 + lane] = oacc[m];
    __syncthreads();
    for (int idx = tid; idx < M_ * 64; idx += 256) {
        const int m = idx >> 6;                    // wave-uniform per iteration
        offs[idx] = ob[m] + u.part[0][idx] + u.part[1][idx]
                          + u.part[2][idx] + u.part[3][idx];
    }
    __syncthreads();

    // ---------------- Phase B: sample + MAC over 4 chunks of 16 channels ----
    float acc[16];
    #pragma unroll
    for (int o = 0; o < 16; ++o) acc[o] = 0.f;
    const int obase = wslot * 16;
    const float flane = (float)lane;

    for (int chunk = 0; chunk < 4; ++chunk) {
        const int cbase = chunk * 16;

        // --- B1: bilinear sampling (this wave: 4 channels x 9 taps) ---
        #pragma unroll
        for (int k = 0; k < KK_; ++k) {
            const int ky = k / 3, kx = k % 3;
            const float offy = offs[(2 * k)     * 64 + lane];
            const float offx = offs[(2 * k + 1) * 64 + lane];
            const float py = (float)(ho - 1 + ky) + offy;
            const float px = (float)(wo_base - 1 + kx) + flane + offx;
            const float fy = floorf(py), fx = floorf(px);
            const int y0 = (int)fy, x0 = (int)fx;
            const int y1 = y0 + 1,  x1 = x0 + 1;
            const float wy1 = py - fy, wy0 = 1.f - wy1;
            const float wx1 = px - fx, wx0 = 1.f - wx1;
            const bool y0v = (unsigned)y0 < (unsigned)H_;
            const bool y1v = (unsigned)y1 < (unsigned)H_;
            const bool x0v = (unsigned)x0 < (unsigned)W_;
            const bool x1v = (unsigned)x1 < (unsigned)W_;
            const float w00 = (y0v && x0v) ? wy0 * wx0 : 0.f;
            const float w01 = (y0v && x1v) ? wy0 * wx1 : 0.f;
            const float w10 = (y1v && x0v) ? wy1 * wx0 : 0.f;
            const float w11 = (y1v && x1v) ? wy1 * wx1 : 0.f;
            const int y0c = min(max(y0, 0), H_ - 1) * W_;
            const int y1c = min(max(y1, 0), H_ - 1) * W_;
            const int x0c = min(max(x0, 0), W_ - 1);
            const int x1c = min(max(x1, 0), W_ - 1);
            const int a00 = y0c + x0c, a01 = y0c + x1c;
            const int a10 = y1c + x0c, a11 = y1c + x1c;
            #pragma unroll
            for (int j = 0; j < 4; ++j) {
                const int cl = wslot * 4 + j;
                const float* xc = xb + (cbase + cl) * HW_;
                const float val = xc[a00] * w00 + xc[a01] * w01
                                + xc[a10] * w10 + xc[a11] * w11;
                u.vals[(cl * 9 + k) * 64 + lane] = val;
            }
        }
        __syncthreads();

        // --- B2: MAC. wt row is wave-uniform -> scalar float4 loads ---
        const int sgbase = cbase * 9;
        #pragma unroll 4
        for (int sl = 0; sl < 144; ++sl) {
            const float v = u.vals[sl * 64 + lane];
            const float4* w4 =
                (const float4*)(wt + (size_t)(sgbase + sl) * O_ + obase);
            const float4 w0 = w4[0], w1 = w4[1], w2 = w4[2], w3 = w4[3];
            acc[0]  += v * w0.x; acc[1]  += v * w0.y;
            acc[2]  += v * w0.z; acc[3]  += v * w0.w;
            acc[4]  += v * w1.x; acc[5]  += v * w1.y;
            acc[6]  += v * w1.z; acc[7]  += v * w1.w;
            acc[8]  += v * w2.x; acc[9]  += v * w2.y;
            acc[10] += v * w2.z; acc[11] += v * w2.w;
            acc[12] += v * w3.x; acc[13] += v * w3.y;
            acc[14] += v * w3.z; acc[15] += v * w3.w;
        }
        __syncthreads();
    }

    // ---------------- Epilogue ----------------
    #pragma unroll
    for (int o = 0; o < 16; ++o) {
        out[(size_t)(b * O_ + obase + o) * HW_ + ho * W_ + wo] =
            acc[o] + bias[obase + o];
    }
}

// ---------------------------------------------------------------------------
extern "C" void kernel_launch(void* const* d_in, const int* in_sizes, int n_in,
                              void* d_out, int out_size, void* d_ws, size_t ws_size,
                              hipStream_t stream) {
    const float* x    = (const float*)d_in[0];  // [4,64,128,128]
    const float* ow   = (const float*)d_in[1];  // [18,64,3,3]
    const float* ob   = (const float*)d_in[2];  // [18]
    const float* w    = (const float*)d_in[3];  // [64,64,3,3]
    const float* bias = (const float*)d_in[4];  // [64]
    float* out = (float*)d_out;                 // [4,64,128,128]

    float* wt  = (float*)d_ws;                  // [576][64]  = 36864 f
    float* owt = wt + 576 * O_;                 // [576][20]  = 11520 f

    repack<<<(576 * O_ + 255) / 256, 256, 0, stream>>>(w, ow, wt, owt);
    dcn_fused<<<B_ * H_ * (W_ / 64), 256, 0, stream>>>(x, owt, ob, wt, bias, out);
}

// Round 3
// 211.724 us; speedup vs baseline: 3.9045x; 1.3928x over previous
//
#include <hip/hip_runtime.h>

// Problem constants (B=4, C=64, H=W=128, O=64, K=3, stride=1, pad=1, dil=1)
#define B_   4
#define C_   64
#define O_   64
#define H_   128
#define W_   128
#define HW_  (H_ * W_)
#define KK_  9
#define M_   18          // 2*KK offset channels
#define OWT_STRIDE 20    // 18 offset-conv weights padded to 20 for float4 loads
#define VS   200         // vals row stride in bf16 elements (400 B: 16B-aligned,
                         // lane-stride 100 words -> 2-way on b128 reads = free)

typedef short  short8  __attribute__((ext_vector_type(8)));
typedef float  floatx4 __attribute__((ext_vector_type(4)));
typedef unsigned short ushort4v __attribute__((ext_vector_type(4)));

static __device__ __forceinline__ unsigned short f2bf(float f) {
    unsigned int u = __float_as_uint(f);
    u += 0x7FFFu + ((u >> 16) & 1u);     // round-to-nearest-even
    return (unsigned short)(u >> 16);
}

// ---------------------------------------------------------------------------
// Repack:
//   wtb[o][tap*64+c] = bf16(w[o][c][tap])   -- MFMA B-fragment layout, k tap-major
//   owt[s][m], s = c*9+tap, m contiguous (stride 20) -- phase-A scalar loads
// ---------------------------------------------------------------------------
__global__ void repack(const float* __restrict__ w, const float* __restrict__ ow,
                       unsigned short* __restrict__ wtb, float* __restrict__ owt) {
    int i = blockIdx.x * blockDim.x + threadIdx.x;
    if (i < 576 * O_) {
        int o = i / 576, r = i % 576;
        int tap = r >> 6, c = r & 63;
        wtb[i] = f2bf(w[o * 576 + c * 9 + tap]);
    }
    if (i < 576 * M_) {
        int s = i / M_, m = i % M_;
        owt[s * OWT_STRIDE + m] = ow[m * 576 + s];
    }
}

// ---------------------------------------------------------------------------
// Fused deformable conv. Block = 64-px row segment, 4 waves, lane = px.
//  Phase A: offset conv (fp32 vector; wave w does channels [16w,16w+16),
//           wave-uniform float4 scalar weight loads, LDS reduce -> offs[18][64])
//  Phase B: 3 chunks of 3 taps x 64 channels (K=192 = 6 MFMA k-steps):
//    B1: sampling. Per tap geometry once; wave w samples channels [16w,16w+16),
//        4-channel-packed b64 bf16 writes into vals[px][k].
//    B2: MAC via mfma_f32_16x16x32_bf16. Wave w owns o-tile [16w,16w+16),
//        iterates 4 px-tiles x 6 k-steps; B-frag = global bf16 load (L2-hot),
//        A-frag = ds_read_b128.
//  Epilogue: acc -> LDS (pad 65) -> coalesced 256B stores + bias.
// ---------------------------------------------------------------------------
__global__ __launch_bounds__(256) void dcn_fused(
        const float* __restrict__ x, const float* __restrict__ owt,
        const float* __restrict__ ob, const unsigned short* __restrict__ wtb,
        const float* __restrict__ bias, float* __restrict__ out) {
    __shared__ union {
        unsigned short vals[64][VS];   // 25600 B  (px-major bf16, k in [0,192))
        float part[4][M_ * 64];        // 18432 B  (phase-A partials)
        float ep[4][16][65];           // 16640 B  (epilogue staging)
    } u;
    __shared__ float offs[M_ * 64];    // 4608 B

    const int tid   = threadIdx.x;
    const int lane  = tid & 63;
    const int wslot = __builtin_amdgcn_readfirstlane(tid >> 6);
    const int wo_base = (blockIdx.x & 1) << 6;
    const int ho = (blockIdx.x >> 1) & (H_ - 1);
    const int b  = blockIdx.x >> 8;
    const int wo = wo_base + lane;
    const float* xb = x + (size_t)b * C_ * HW_;

    // ---------------- Phase A: offset conv ----------------
    float oacc[M_];
    #pragma unroll
    for (int m = 0; m < M_; ++m) oacc[m] = 0.f;

    for (int cl = 0; cl < 16; ++cl) {
        const int c = wslot * 16 + cl;
        const float* xc = xb + c * HW_;
        #pragma unroll
        for (int ky = 0; ky < 3; ++ky) {
            const int y = ho - 1 + ky;
            const bool yv = (unsigned)y < (unsigned)H_;
            #pragma unroll
            for (int kx = 0; kx < 3; ++kx) {
                const int col = wo - 1 + kx;
                const float xv =
                    (yv && (unsigned)col < (unsigned)W_) ? xc[y * W_ + col] : 0.f;
                const float* wr = owt + (c * 9 + ky * 3 + kx) * OWT_STRIDE;
                const float4* w4 = (const float4*)wr;      // wave-uniform -> s_load
                const float4 wa = w4[0], wb = w4[1], wc = w4[2], wd = w4[3];
                const float we = wr[16], wf = wr[17];
                oacc[0]  += xv * wa.x; oacc[1]  += xv * wa.y;
                oacc[2]  += xv * wa.z; oacc[3]  += xv * wa.w;
                oacc[4]  += xv * wb.x; oacc[5]  += xv * wb.y;
                oacc[6]  += xv * wb.z; oacc[7]  += xv * wb.w;
                oacc[8]  += xv * wc.x; oacc[9]  += xv * wc.y;
                oacc[10] += xv * wc.z; oacc[11] += xv * wc.w;
                oacc[12] += xv * wd.x; oacc[13] += xv * wd.y;
                oacc[14] += xv * wd.z; oacc[15] += xv * wd.w;
                oacc[16] += xv * we;   oacc[17] += xv * wf;
            }
        }
    }
    #pragma unroll
    for (int m = 0; m < M_; ++m) u.part[wslot][m * 64 + lane] = oacc[m];
    __syncthreads();
    for (int idx = tid; idx < M_ * 64; idx += 256) {
        const int m = idx >> 6;                    // wave-uniform per iteration
        offs[idx] = ob[m] + u.part[0][idx] + u.part[1][idx]
                          + u.part[2][idx] + u.part[3][idx];
    }
    __syncthreads();

    // ---------------- Phase B: sample (bf16->LDS) + MFMA MAC ----------------
    const int col  = lane & 15;        // px_local for A/D rows; o_local for B cols
    const int quad = lane >> 4;
    const int obase = wslot * 16;
    floatx4 acc[4];
    #pragma unroll
    for (int t = 0; t < 4; ++t) acc[t] = (floatx4){0.f, 0.f, 0.f, 0.f};
    const float flane = (float)lane;

    for (int chunk = 0; chunk < 3; ++chunk) {
        // --- B1: sampling, 3 taps x 16 channels per wave ---
        #pragma unroll
        for (int tl = 0; tl < 3; ++tl) {
            const int k  = chunk * 3 + tl;         // global tap 0..8
            const int ky = k / 3, kx = k % 3;
            const float offy = offs[(2 * k)     * 64 + lane];
            const float offx = offs[(2 * k + 1) * 64 + lane];
            const float py = (float)(ho - 1 + ky) + offy;
            const float px = (float)(wo_base - 1 + kx) + flane + offx;
            const float fy = floorf(py), fx = floorf(px);
            const int y0 = (int)fy, x0 = (int)fx;
            const int y1 = y0 + 1,  x1 = x0 + 1;
            const float wy1 = py - fy, wy0 = 1.f - wy1;
            const float wx1 = px - fx, wx0 = 1.f - wx1;
            const bool y0v = (unsigned)y0 < (unsigned)H_;
            const bool y1v = (unsigned)y1 < (unsigned)H_;
            const bool x0v = (unsigned)x0 < (unsigned)W_;
            const bool x1v = (unsigned)x1 < (unsigned)W_;
            const float w00 = (y0v && x0v) ? wy0 * wx0 : 0.f;
            const float w01 = (y0v && x1v) ? wy0 * wx1 : 0.f;
            const float w10 = (y1v && x0v) ? wy1 * wx0 : 0.f;
            const float w11 = (y1v && x1v) ? wy1 * wx1 : 0.f;
            const int y0c = min(max(y0, 0), H_ - 1) * W_;
            const int y1c = min(max(y1, 0), H_ - 1) * W_;
            const int x0c = min(max(x0, 0), W_ - 1);
            const int x1c = min(max(x1, 0), W_ - 1);
            const int a00 = y0c + x0c, a01 = y0c + x1c;
            const int a10 = y1c + x0c, a11 = y1c + x1c;
            #pragma unroll
            for (int j = 0; j < 4; ++j) {          // 4 channels per b64 write
                ushort4v pk;
                #pragma unroll
                for (int q = 0; q < 4; ++q) {
                    const int c = wslot * 16 + j * 4 + q;
                    const float* xc = xb + c * HW_;
                    const float val = xc[a00] * w00 + xc[a01] * w01
                                    + xc[a10] * w10 + xc[a11] * w11;
                    pk[q] = f2bf(val);
                }
                // k_local = tl*64 + c ; 8B-aligned
                *(ushort4v*)&u.vals[lane][tl * 64 + wslot * 16 + j * 4] = pk;
            }
        }
        __syncthreads();

        // --- B2: MFMA MAC. 6 k-steps x 4 px-tiles ---
        const unsigned short* wrow = wtb + (size_t)(obase + col) * 576 + chunk * 192;
        #pragma unroll
        for (int ks = 0; ks < 6; ++ks) {
            const int kk = ks * 32 + quad * 8;
            const short8 bfrag = *(const short8*)(wrow + kk);
            #pragma unroll
            for (int t = 0; t < 4; ++t) {
                const short8 afrag = *(const short8*)&u.vals[t * 16 + col][kk];
                acc[t] = __builtin_amdgcn_mfma_f32_16x16x32_bf16(
                             afrag, bfrag, acc[t], 0, 0, 0);
            }
        }
        __syncthreads();
    }

    // ---------------- Epilogue: stage via LDS, coalesced store ----------------
    #pragma unroll
    for (int t = 0; t < 4; ++t)
        #pragma unroll
        for (int r = 0; r < 4; ++r)
            u.ep[wslot][col][t * 16 + quad * 4 + r] = acc[t][r];
    __syncthreads();
    #pragma unroll
    for (int oi = 0; oi < 16; ++oi) {
        const int o = obase + oi;
        out[(size_t)(b * O_ + o) * HW_ + ho * W_ + wo_base + lane] =
            u.ep[wslot][oi][lane] + bias[o];
    }
}

// ---------------------------------------------------------------------------
extern "C" void kernel_launch(void* const* d_in, const int* in_sizes, int n_in,
                              void* d_out, int out_size, void* d_ws, size_t ws_size,
                              hipStream_t stream) {
    const float* x    = (const float*)d_in[0];  // [4,64,128,128]
    const float* ow   = (const float*)d_in[1];  // [18,64,3,3]
    const float* ob   = (const float*)d_in[2];  // [18]
    const float* w    = (const float*)d_in[3];  // [64,64,3,3]
    const float* bias = (const float*)d_in[4];  // [64]
    float* out = (float*)d_out;                 // [4,64,128,128]

    float* owt = (float*)d_ws;                          // [576][20] f32
    unsigned short* wtb = (unsigned short*)(owt + 576 * OWT_STRIDE);  // [64][576] bf16

    repack<<<(576 * O_ + 255) / 256, 256, 0, stream>>>(w, ow, wtb, owt);
    dcn_fused<<<B_ * H_ * (W_ / 64), 256, 0, stream>>>(x, owt, ob, wtb, bias, out);
}

// Round 4
// 208.092 us; speedup vs baseline: 3.9726x; 1.0175x over previous
//
#include <hip/hip_runtime.h>

// Problem constants (B=4, C=64, H=W=128, O=64, K=3, stride=1, pad=1, dil=1)
#define B_   4
#define C_   64
#define O_   64
#define H_   128
#define W_   128
#define HW_  (H_ * W_)
#define KK_  9
#define M_   18          // 2*KK offset channels
#define OWT_STRIDE 20    // 18 offset-conv weights padded to 20 for float4 loads

typedef short  short8  __attribute__((ext_vector_type(8)));
typedef float  floatx4 __attribute__((ext_vector_type(4)));
typedef unsigned short ushort8v __attribute__((ext_vector_type(8)));

static __device__ __forceinline__ unsigned short f2bf(float f) {
    unsigned int u = __float_as_uint(f);
    u += 0x7FFFu + ((u >> 16) & 1u);     // round-to-nearest-even
    return (unsigned short)(u >> 16);
}

// ---------------------------------------------------------------------------
// Repack:
//   wtb[o][tap*64+c] = bf16(w[o][c][tap])   -- MFMA B-fragment layout, k tap-major
//   owt[s][m], s = c*9+tap, m contiguous (stride 20) -- phase-A scalar loads
// ---------------------------------------------------------------------------
__global__ void repack(const float* __restrict__ w, const float* __restrict__ ow,
                       unsigned short* __restrict__ wtb, float* __restrict__ owt) {
    int i = blockIdx.x * blockDim.x + threadIdx.x;
    if (i < 576 * O_) {
        int o = i / 576, r = i % 576;
        int tap = r >> 6, c = r & 63;
        wtb[i] = f2bf(w[o * 576 + c * 9 + tap]);
    }
    if (i < 576 * M_) {
        int s = i / M_, m = i % M_;
        owt[s * OWT_STRIDE + m] = ow[m * 576 + s];
    }
}

// ---------------------------------------------------------------------------
// Fused deformable conv. Block = 64-px row segment, 4 waves, lane = px.
// Block->XCD banding: blockIdx%8 = XCD (HW round-robin); XCD x owns rows
// [16x,16x+16) for all (b,half) -> per-XCD x working set ~2.6MB fits 4MB L2.
//
// vals LDS layout: [row 0..63][192 shorts], 16-B chunks XOR-swizzled by row&7
// -> b128 reads AND b128 writes hit all 32 banks at the 8-access minimum.
// ---------------------------------------------------------------------------
__global__ __launch_bounds__(256) void dcn_fused(
        const float* __restrict__ x, const float* __restrict__ owt,
        const float* __restrict__ ob, const unsigned short* __restrict__ wtb,
        const float* __restrict__ bias, float* __restrict__ out) {
    __shared__ union {
        unsigned short vals[64][192];  // 24576 B (swizzled, k in [0,192))
        float part[4][M_ * 64];        // 18432 B (phase-A partials)
        float ep[4][16][65];           // 16640 B (epilogue staging)
    } u;
    __shared__ float offs[M_ * 64];    // 4608 B

    const int tid   = threadIdx.x;
    const int lane  = tid & 63;
    const int wslot = __builtin_amdgcn_readfirstlane(tid >> 6);

    // XCD-banded remap (g%8 = XCD): XCD x -> rows [16x,16x+16), all b/half
    const int g    = blockIdx.x;
    const int xcd  = g & 7;
    const int slot = g >> 3;
    const int ho   = xcd * 16 + (slot >> 3);
    const int b    = (slot >> 1) & 3;
    const int wo_base = (slot & 1) << 6;

    const int wo = wo_base + lane;
    const float* xb = x + (size_t)b * C_ * HW_;

    // ---------------- Phase A: offset conv ----------------
    float oacc[M_];
    #pragma unroll
    for (int m = 0; m < M_; ++m) oacc[m] = 0.f;

    for (int cl = 0; cl < 16; ++cl) {
        const int c = wslot * 16 + cl;
        const float* xc = xb + c * HW_;
        #pragma unroll
        for (int ky = 0; ky < 3; ++ky) {
            const int y = ho - 1 + ky;
            const bool yv = (unsigned)y < (unsigned)H_;
            #pragma unroll
            for (int kx = 0; kx < 3; ++kx) {
                const int col = wo - 1 + kx;
                const float xv =
                    (yv && (unsigned)col < (unsigned)W_) ? xc[y * W_ + col] : 0.f;
                const float* wr = owt + (c * 9 + ky * 3 + kx) * OWT_STRIDE;
                const float4* w4 = (const float4*)wr;      // wave-uniform -> s_load
                const float4 wa = w4[0], wb = w4[1], wc = w4[2], wd = w4[3];
                const float we = wr[16], wf = wr[17];
                oacc[0]  += xv * wa.x; oacc[1]  += xv * wa.y;
                oacc[2]  += xv * wa.z; oacc[3]  += xv * wa.w;
                oacc[4]  += xv * wb.x; oacc[5]  += xv * wb.y;
                oacc[6]  += xv * wb.z; oacc[7]  += xv * wb.w;
                oacc[8]  += xv * wc.x; oacc[9]  += xv * wc.y;
                oacc[10] += xv * wc.z; oacc[11] += xv * wc.w;
                oacc[12] += xv * wd.x; oacc[13] += xv * wd.y;
                oacc[14] += xv * wd.z; oacc[15] += xv * wd.w;
                oacc[16] += xv * we;   oacc[17] += xv * wf;
            }
        }
    }
    #pragma unroll
    for (int m = 0; m < M_; ++m) u.part[wslot][m * 64 + lane] = oacc[m];
    __syncthreads();
    for (int idx = tid; idx < M_ * 64; idx += 256) {
        const int m = idx >> 6;                    // wave-uniform per iteration
        offs[idx] = ob[m] + u.part[0][idx] + u.part[1][idx]
                          + u.part[2][idx] + u.part[3][idx];
    }
    __syncthreads();

    // ---------------- Phase B: sample (bf16->LDS) + MFMA MAC ----------------
    const int col  = lane & 15;        // px_local for A/D rows; o_local for B cols
    const int quad = lane >> 4;
    const int obase = wslot * 16;
    floatx4 acc[4];
    #pragma unroll
    for (int t = 0; t < 4; ++t) acc[t] = (floatx4){0.f, 0.f, 0.f, 0.f};
    const float flane = (float)lane;

    for (int chunk = 0; chunk < 3; ++chunk) {
        // --- B1: sampling, 3 taps x 16 channels per wave ---
        #pragma unroll
        for (int tl = 0; tl < 3; ++tl) {
            const int k  = chunk * 3 + tl;         // global tap 0..8
            const int ky = k / 3, kx = k % 3;
            const float offy = offs[(2 * k)     * 64 + lane];
            const float offx = offs[(2 * k + 1) * 64 + lane];
            const float py = (float)(ho - 1 + ky) + offy;
            const float px = (float)(wo_base - 1 + kx) + flane + offx;
            const float fy = floorf(py), fx = floorf(px);
            const int y0 = (int)fy, x0 = (int)fx;
            const int y1 = y0 + 1,  x1 = x0 + 1;
            const float wy1 = py - fy, wy0 = 1.f - wy1;
            const float wx1 = px - fx, wx0 = 1.f - wx1;
            const bool y0v = (unsigned)y0 < (unsigned)H_;
            const bool y1v = (unsigned)y1 < (unsigned)H_;
            const bool x0v = (unsigned)x0 < (unsigned)W_;
            const bool x1v = (unsigned)x1 < (unsigned)W_;
            const float w00 = (y0v && x0v) ? wy0 * wx0 : 0.f;
            const float w01 = (y0v && x1v) ? wy0 * wx1 : 0.f;
            const float w10 = (y1v && x0v) ? wy1 * wx0 : 0.f;
            const float w11 = (y1v && x1v) ? wy1 * wx1 : 0.f;
            const int y0c = min(max(y0, 0), H_ - 1) * W_;
            const int y1c = min(max(y1, 0), H_ - 1) * W_;
            const int x0c = min(max(x0, 0), W_ - 1);
            const int x1c = min(max(x1, 0), W_ - 1);
            const int a00 = y0c + x0c, a01 = y0c + x1c;
            const int a10 = y1c + x0c, a11 = y1c + x1c;
            #pragma unroll
            for (int j = 0; j < 2; ++j) {          // 8 channels per b128 write
                ushort8v pk;
                #pragma unroll
                for (int q = 0; q < 8; ++q) {
                    const int c = wslot * 16 + j * 8 + q;
                    const float* xc = xb + c * HW_;
                    const float val = xc[a00] * w00 + xc[a01] * w01
                                    + xc[a10] * w10 + xc[a11] * w11;
                    pk[q] = f2bf(val);
                }
                // chunk index tl*8 + (wslot*2+j), low 3 bits XOR row&7
                const int cb = (wslot * 2 + j) ^ (lane & 7);
                *(ushort8v*)&u.vals[lane][(tl * 8 + cb) * 8] = pk;
            }
        }
        __syncthreads();

        // --- B2: MFMA MAC. 6 k-steps x 4 px-tiles ---
        const unsigned short* wrow = wtb + (size_t)(obase + col) * 576 + chunk * 192;
        #pragma unroll
        for (int ks = 0; ks < 6; ++ks) {
            const int kk = ks * 32 + quad * 8;
            const short8 bfrag = *(const short8*)(wrow + kk);
            const int ca = (ks * 4 + quad) >> 3;       // chunk group
            const int cbr = ((ks * 4 + quad) & 7) ^ (col & 7);  // swizzled low bits
            #pragma unroll
            for (int t = 0; t < 4; ++t) {
                const int row = t * 16 + col;
                const short8 afrag =
                    *(const short8*)&u.vals[row][(ca * 8 + cbr) * 8];
                acc[t] = __builtin_amdgcn_mfma_f32_16x16x32_bf16(
                             afrag, bfrag, acc[t], 0, 0, 0);
            }
        }
        __syncthreads();
    }

    // ---------------- Epilogue: stage via LDS, coalesced store ----------------
    #pragma unroll
    for (int t = 0; t < 4; ++t)
        #pragma unroll
        for (int r = 0; r < 4; ++r)
            u.ep[wslot][col][t * 16 + quad * 4 + r] = acc[t][r];
    __syncthreads();
    #pragma unroll
    for (int oi = 0; oi < 16; ++oi) {
        const int o = obase + oi;
        out[(size_t)(b * O_ + o) * HW_ + ho * W_ + wo_base + lane] =
            u.ep[wslot][oi][lane] + bias[o];
    }
}

// ---------------------------------------------------------------------------
extern "C" void kernel_launch(void* const* d_in, const int* in_sizes, int n_in,
                              void* d_out, int out_size, void* d_ws, size_t ws_size,
                              hipStream_t stream) {
    const float* x    = (const float*)d_in[0];  // [4,64,128,128]
    const float* ow   = (const float*)d_in[1];  // [18,64,3,3]
    const float* ob   = (const float*)d_in[2];  // [18]
    const float* w    = (const float*)d_in[3];  // [64,64,3,3]
    const float* bias = (const float*)d_in[4];  // [64]
    float* out = (float*)d_out;                 // [4,64,128,128]

    float* owt = (float*)d_ws;                          // [576][20] f32
    unsigned short* wtb = (unsigned short*)(owt + 576 * OWT_STRIDE);  // [64][576] bf16

    repack<<<(576 * O_ + 255) / 256, 256, 0, stream>>>(w, ow, wtb, owt);
    dcn_fused<<<B_ * H_ * (W_ / 64), 256, 0, stream>>>(x, owt, ob, wtb, bias, out);
}

// Round 5
// 181.891 us; speedup vs baseline: 4.5449x; 1.1440x over previous
//
#include <hip/hip_runtime.h>

// Problem constants (B=4, C=64, H=W=128, O=64, K=3, stride=1, pad=1, dil=1)
#define B_   4
#define C_   64
#define O_   64
#define H_   128
#define W_   128
#define HW_  (H_ * W_)
#define KK_  9
#define M_   18          // 2*KK offset channels

typedef short  short8  __attribute__((ext_vector_type(8)));
typedef float  floatx4 __attribute__((ext_vector_type(4)));
typedef unsigned short ushort8v __attribute__((ext_vector_type(8)));

static __device__ __forceinline__ unsigned short f2bf(float f) {
    unsigned int u = __float_as_uint(f);
    u += 0x7FFFu + ((u >> 16) & 1u);     // round-to-nearest-even
    return (unsigned short)(u >> 16);
}

// ---------------------------------------------------------------------------
// Repack (bf16):
//   wtb [o][tap*64+c]          -- main-conv B-frag layout (k tap-major)
//   owtb[tap][m(32,pad)][c]    -- offset-conv B-frag layout (8 contiguous c)
// ---------------------------------------------------------------------------
__global__ void repack(const float* __restrict__ w, const float* __restrict__ ow,
                       unsigned short* __restrict__ wtb,
                       unsigned short* __restrict__ owtb) {
    int i = blockIdx.x * blockDim.x + threadIdx.x;
    if (i < 576 * O_) {
        int o = i / 576, r = i % 576;
        int tap = r >> 6, c = r & 63;
        wtb[i] = f2bf(w[o * 576 + c * 9 + tap]);
    }
    if (i < 9 * 32 * 64) {
        int tap = i >> 11, m = (i >> 6) & 31, c = i & 63;
        owtb[i] = (m < M_) ? f2bf(ow[m * 576 + c * 9 + tap]) : (unsigned short)0;
    }
}

// ---------------------------------------------------------------------------
// Fused deformable conv. Block = 64-px row segment, 4 waves, lane = px.
// XCD banding (blockIdx%8 = XCD): XCD x owns rows [16x,16x+16) -> x slice
// stays resident in the 4MB per-XCD L2 (round 4: FETCH 197MB -> 10.8MB).
//
// Phase A (MFMA offset conv): stage x rows ho-1..ho+1 as bf16 P[3][66][72]
// (px-major, channel-contiguous; row stride 144B). The 3x3 im2col is 9
// shifted views of P -> offs[18][64] = 9 taps x 2 ksteps of 16x16x32 MFMA
// per px-tile (wave = px-tile), 2 m-tiles (18 padded to 32).
// Phase B: per 3-tap chunk: bilinear sample -> bf16 vals (XOR-swizzled),
// then 16x16x32 MFMA against wtb.
// ---------------------------------------------------------------------------
__global__ __launch_bounds__(256) void dcn_fused(
        const float* __restrict__ x, const unsigned short* __restrict__ owtb,
        const float* __restrict__ ob, const unsigned short* __restrict__ wtb,
        const float* __restrict__ bias, float* __restrict__ out) {
    __shared__ union {
        unsigned short P[3][66][72];   // 28512 B (phase-A row staging)
        unsigned short vals[64][192];  // 24576 B (phase-B, swizzled)
        float ep[4][16][65];           // 16640 B (epilogue staging)
    } u;
    __shared__ float offs[M_ * 64];    // 4608 B  (conv only; bias added at use)

    const int tid    = threadIdx.x;
    const int lane   = tid & 63;
    const int wslot  = __builtin_amdgcn_readfirstlane(tid >> 6);
    const int lane15 = lane & 15;
    const int quad   = lane >> 4;

    // XCD-banded remap (g%8 = XCD): XCD x -> rows [16x,16x+16), all b/half
    const int g    = blockIdx.x;
    const int xcd  = g & 7;
    const int slot = g >> 3;
    const int ho   = xcd * 16 + (slot >> 3);
    const int b    = (slot >> 1) & 3;
    const int wo_base = (slot & 1) << 6;

    const float* xb = x + (size_t)b * C_ * HW_;

    // ---------------- Phase A1: stage 3 x-rows into P (bf16) ----------------
    // P[ky][r][c] = x[c][ho-1+ky][wo_base + r - 1],  r in [0,66)
    for (int t = wslot; t < 24; t += 4) {          // 24 tasks: (ky, 8-ch octet)
        const int ky = t >> 3, o8 = t & 7;
        const int y  = ho - 1 + ky;
        const bool yv = (unsigned)y < (unsigned)H_;
        const float* xrow = xb + (size_t)(o8 * 8) * HW_ + y * W_;
        #pragma unroll
        for (int pass = 0; pass < 2; ++pass) {
            const int r = pass * 64 + lane;
            if (r < 66) {
                const int cx = wo_base + r - 1;
                const bool v = yv && (unsigned)cx < (unsigned)W_;
                ushort8v pk;
                #pragma unroll
                for (int j = 0; j < 8; ++j) {
                    const float f = v ? xrow[j * HW_ + cx] : 0.f;
                    pk[j] = f2bf(f);
                }
                *(ushort8v*)&u.P[ky][r][o8 * 8] = pk;
            }
        }
    }
    __syncthreads();

    // ---------------- Phase A2: offs = MFMA offset conv ----------------
    // wave = px-tile (16 px); A[px][c] = P[ky][px+kx][c]; B = owtb[tap][m][c]
    {
        floatx4 oa0 = (floatx4){0.f, 0.f, 0.f, 0.f};
        floatx4 oa1 = (floatx4){0.f, 0.f, 0.f, 0.f};
        const int pxt = wslot;
        #pragma unroll
        for (int ky = 0; ky < 3; ++ky) {
            #pragma unroll
            for (int kx = 0; kx < 3; ++kx) {
                const int tap = ky * 3 + kx;
                #pragma unroll
                for (int ks = 0; ks < 2; ++ks) {
                    const int kk = ks * 32 + quad * 8;
                    const short8 af =
                        *(const short8*)&u.P[ky][pxt * 16 + lane15 + kx][kk];
                    const short8 bf0 =
                        *(const short8*)&owtb[(size_t)(tap * 32 + lane15) * 64 + kk];
                    const short8 bf1 =
                        *(const short8*)&owtb[(size_t)(tap * 32 + 16 + lane15) * 64 + kk];
                    oa0 = __builtin_amdgcn_mfma_f32_16x16x32_bf16(af, bf0, oa0, 0, 0, 0);
                    oa1 = __builtin_amdgcn_mfma_f32_16x16x32_bf16(af, bf1, oa1, 0, 0, 0);
                }
            }
        }
        // D[px=quad*4+r][m=lane15] -> offs[m][px]  (b128, px contiguous)
        *(floatx4*)&offs[lane15 * 64 + pxt * 16 + quad * 4] = oa0;
        if (lane15 < 2)
            *(floatx4*)&offs[(16 + lane15) * 64 + pxt * 16 + quad * 4] = oa1;
    }
    __syncthreads();

    // ---------------- Phase B: sample (bf16->LDS) + MFMA MAC ----------------
    const int obase = wslot * 16;
    floatx4 acc[4];
    #pragma unroll
    for (int t = 0; t < 4; ++t) acc[t] = (floatx4){0.f, 0.f, 0.f, 0.f};
    const float flane = (float)lane;

    for (int chunk = 0; chunk < 3; ++chunk) {
        // --- B1: sampling, 3 taps x 16 channels per wave ---
        #pragma unroll
        for (int tl = 0; tl < 3; ++tl) {
            const int k  = chunk * 3 + tl;         // global tap 0..8
            const int ky = k / 3, kx = k % 3;
            const float offy = offs[(2 * k)     * 64 + lane] + ob[2 * k];
            const float offx = offs[(2 * k + 1) * 64 + lane] + ob[2 * k + 1];
            const float py = (float)(ho - 1 + ky) + offy;
            const float px = (float)(wo_base - 1 + kx) + flane + offx;
            const float fy = floorf(py), fx = floorf(px);
            const int y0 = (int)fy, x0 = (int)fx;
            const int y1 = y0 + 1,  x1 = x0 + 1;
            const float wy1 = py - fy, wy0 = 1.f - wy1;
            const float wx1 = px - fx, wx0 = 1.f - wx1;
            const bool y0v = (unsigned)y0 < (unsigned)H_;
            const bool y1v = (unsigned)y1 < (unsigned)H_;
            const bool x0v = (unsigned)x0 < (unsigned)W_;
            const bool x1v = (unsigned)x1 < (unsigned)W_;
            const float w00 = (y0v && x0v) ? wy0 * wx0 : 0.f;
            const float w01 = (y0v && x1v) ? wy0 * wx1 : 0.f;
            const float w10 = (y1v && x0v) ? wy1 * wx0 : 0.f;
            const float w11 = (y1v && x1v) ? wy1 * wx1 : 0.f;
            const int y0c = min(max(y0, 0), H_ - 1) * W_;
            const int y1c = min(max(y1, 0), H_ - 1) * W_;
            const int x0c = min(max(x0, 0), W_ - 1);
            const int x1c = min(max(x1, 0), W_ - 1);
            const int a00 = y0c + x0c, a01 = y0c + x1c;
            const int a10 = y1c + x0c, a11 = y1c + x1c;
            #pragma unroll
            for (int j = 0; j < 2; ++j) {          // 8 channels per b128 write
                ushort8v pk;
                #pragma unroll
                for (int q = 0; q < 8; ++q) {
                    const int c = wslot * 16 + j * 8 + q;
                    const float* xc = xb + (size_t)c * HW_;
                    const float val = xc[a00] * w00 + xc[a01] * w01
                                    + xc[a10] * w10 + xc[a11] * w11;
                    pk[q] = f2bf(val);
                }
                // chunk index tl*8 + (wslot*2+j), low 3 bits XOR row&7
                const int cb = (wslot * 2 + j) ^ (lane & 7);
                *(ushort8v*)&u.vals[lane][(tl * 8 + cb) * 8] = pk;
            }
        }
        __syncthreads();

        // --- B2: MFMA MAC. 6 k-steps x 4 px-tiles ---
        const unsigned short* wrow =
            wtb + (size_t)(obase + lane15) * 576 + chunk * 192;
        #pragma unroll
        for (int ks = 0; ks < 6; ++ks) {
            const int kk = ks * 32 + quad * 8;
            const short8 bfrag = *(const short8*)(wrow + kk);
            const int ca  = (ks * 4 + quad) >> 3;                    // chunk group
            const int cbr = ((ks * 4 + quad) & 7) ^ (lane15 & 7);    // swizzled
            #pragma unroll
            for (int t = 0; t < 4; ++t) {
                const int row = t * 16 + lane15;
                const short8 afrag =
                    *(const short8*)&u.vals[row][(ca * 8 + cbr) * 8];
                acc[t] = __builtin_amdgcn_mfma_f32_16x16x32_bf16(
                             afrag, bfrag, acc[t], 0, 0, 0);
            }
        }
        __syncthreads();
    }

    // ---------------- Epilogue: stage via LDS, coalesced store ----------------
    #pragma unroll
    for (int t = 0; t < 4; ++t)
        #pragma unroll
        for (int r = 0; r < 4; ++r)
            u.ep[wslot][lane15][t * 16 + quad * 4 + r] = acc[t][r];
    __syncthreads();
    #pragma unroll
    for (int oi = 0; oi < 16; ++oi) {
        const int o = obase + oi;
        out[(size_t)(b * O_ + o) * HW_ + ho * W_ + wo_base + lane] =
            u.ep[wslot][oi][lane] + bias[o];
    }
}

// ---------------------------------------------------------------------------
extern "C" void kernel_launch(void* const* d_in, const int* in_sizes, int n_in,
                              void* d_out, int out_size, void* d_ws, size_t ws_size,
                              hipStream_t stream) {
    const float* x    = (const float*)d_in[0];  // [4,64,128,128]
    const float* ow   = (const float*)d_in[1];  // [18,64,3,3]
    const float* ob   = (const float*)d_in[2];  // [18]
    const float* w    = (const float*)d_in[3];  // [64,64,3,3]
    const float* bias = (const float*)d_in[4];  // [64]
    float* out = (float*)d_out;                 // [4,64,128,128]

    unsigned short* wtb  = (unsigned short*)d_ws;     // [64][576] bf16
    unsigned short* owtb = wtb + 576 * O_;            // [9][32][64] bf16

    repack<<<(576 * O_ + 255) / 256, 256, 0, stream>>>(w, ow, wtb, owtb);
    dcn_fused<<<B_ * H_ * (W_ / 64), 256, 0, stream>>>(x, owtb, ob, wtb, bias, out);
}

// Round 6
// 129.821 us; speedup vs baseline: 6.3678x; 1.4011x over previous
//
#include <hip/hip_runtime.h>

// Problem constants (B=4, C=64, H=W=128, O=64, K=3, stride=1, pad=1, dil=1)
#define B_   4
#define C_   64
#define O_   64
#define H_   128
#define W_   128
#define HW_  (H_ * W_)
#define KK_  9
#define M_   18          // 2*KK offset channels

typedef short  short8  __attribute__((ext_vector_type(8)));
typedef float  floatx4 __attribute__((ext_vector_type(4)));
typedef unsigned short ushort4v __attribute__((ext_vector_type(4)));
typedef unsigned short ushort8v __attribute__((ext_vector_type(8)));

static __device__ __forceinline__ unsigned short f2bf(float f) {
    unsigned int u = __float_as_uint(f);
    u += 0x7FFFu + ((u >> 16) & 1u);     // round-to-nearest-even
    return (unsigned short)(u >> 16);
}
static __device__ __forceinline__ float bf2f(unsigned short s) {
    return __uint_as_float((unsigned int)s << 16);
}

// ---------------------------------------------------------------------------
// Repack (bf16):
//   wtb [o][tap*64+c]          -- main-conv B-frag layout (k tap-major)
//   owtb[tap][m(32,pad)][c]    -- offset-conv B-frag layout
// ---------------------------------------------------------------------------
__global__ void repack(const float* __restrict__ w, const float* __restrict__ ow,
                       unsigned short* __restrict__ wtb,
                       unsigned short* __restrict__ owtb) {
    int i = blockIdx.x * blockDim.x + threadIdx.x;
    if (i < 576 * O_) {
        int o = i / 576, r = i % 576;
        int tap = r >> 6, c = r & 63;
        wtb[i] = f2bf(w[o * 576 + c * 9 + tap]);
    }
    if (i < 9 * 32 * 64) {
        int tap = i >> 11, m = (i >> 6) & 31, c = i & 63;
        owtb[i] = (m < M_) ? f2bf(ow[m * 576 + c * 9 + tap]) : (unsigned short)0;
    }
}

// ---------------------------------------------------------------------------
// Channel-interleave transpose: xT[b][g][y][x][c16] bf16 (g = c>>4, c16 = c&15).
// One corner (y,x) for 4 consecutive channels = one aligned 8 B load in dcn.
// Block = (b, y); LDS-tiled so both global read and write are coalesced.
// ---------------------------------------------------------------------------
__global__ __launch_bounds__(256) void xpose(const float* __restrict__ x,
                                             unsigned short* __restrict__ xT) {
    __shared__ unsigned short T[128][72];   // [x][c], row padded to 72
    const int tid = threadIdx.x;
    const int y = blockIdx.x & (H_ - 1);
    const int b = blockIdx.x >> 7;
    const float* xby = x + (size_t)b * C_ * HW_ + y * W_;
    for (int i = tid; i < C_ * W_; i += 256) {
        const int c = i >> 7, xc = i & 127;
        T[xc][c] = f2bf(xby[(size_t)c * HW_ + xc]);
    }
    __syncthreads();
    unsigned short* dst = xT + (size_t)b * (4 * HW_ * 16) + y * (W_ * 16);
    for (int j = tid; j < 2048; j += 256) {
        const int g  = j >> 9;
        const int x8 = (j >> 2) & 127;
        const int c0 = (j & 3) * 4;
        const ushort4v pk = *(const ushort4v*)&T[x8][g * 16 + c0];
        *(ushort4v*)&dst[(size_t)g * (HW_ * 16) + x8 * 16 + c0] = pk;
    }
}

// ---------------------------------------------------------------------------
// Fused deformable conv. Block = 64-px row segment, 4 waves.
// XCD banding (blockIdx%8 = XCD): XCD x owns rows [16x,16x+16) -> x/xT slice
// L2-resident per XCD (round 4: FETCH 197MB -> 10.8MB).
//
// Phase A: stage P[3][66][72] (bf16, c-contig) from xT with contiguous 32B/lane
//          copies; offs = MFMA offset conv (round 5).
// Phase B: wave = 16-channel slice; lane = (px16, cg4). Per (tap, px-tile):
//          4 corner loads of 8 B (4 channels each) from xT -> bilinear in fp32
//          -> bf16 vals (XOR-swizzled) -> 16x16x32 MFMA against wtb.
// ---------------------------------------------------------------------------
__global__ __launch_bounds__(256, 4) void dcn_fused(
        const unsigned short* __restrict__ xT,
        const unsigned short* __restrict__ owtb, const float* __restrict__ ob,
        const unsigned short* __restrict__ wtb, const float* __restrict__ bias,
        float* __restrict__ out) {
    __shared__ union {
        unsigned short P[3][66][72];   // 28512 B (phase-A row staging)
        unsigned short vals[64][192];  // 24576 B (phase-B, swizzled)
        float ep[4][16][65];           // 16640 B (epilogue staging)
    } u;
    __shared__ float offs[M_ * 64];    // 4608 B  (conv only; bias added at use)

    const int tid    = threadIdx.x;
    const int lane   = tid & 63;
    const int wslot  = __builtin_amdgcn_readfirstlane(tid >> 6);
    const int lane15 = lane & 15;
    const int quad   = lane >> 4;

    // XCD-banded remap (g%8 = XCD): XCD x -> rows [16x,16x+16), all b/half
    const int g    = blockIdx.x;
    const int xcd  = g & 7;
    const int slot = g >> 3;
    const int ho   = xcd * 16 + (slot >> 3);
    const int b    = (slot >> 1) & 3;
    const int wo_base = (slot & 1) << 6;

    const unsigned short* xTb = xT + (size_t)b * (4 * HW_ * 16);

    // ---------------- Phase A1: stage 3 x-rows into P from xT ----------------
    // P[ky][r][c] = x[c][ho-1+ky][wo_base + r - 1],  r in [0,66)
    #pragma unroll
    for (int it = 0; it < 3; ++it) {
        const int t  = it * 4 + wslot;         // 0..11 = (ky, channel-group)
        const int ky = t >> 2, cgp = t & 3;
        const int y  = ho - 1 + ky;
        const bool yv = (unsigned)y < (unsigned)H_;
        const unsigned short* src = xTb + (size_t)cgp * (HW_ * 16) + y * (W_ * 16);
        #pragma unroll
        for (int pass = 0; pass < 2; ++pass) {
            const int r = pass * 64 + lane;
            if (r < 66) {
                const int cx = wo_base + r - 1;
                ushort8v p0 = {0, 0, 0, 0, 0, 0, 0, 0};
                ushort8v p1 = {0, 0, 0, 0, 0, 0, 0, 0};
                if (yv && (unsigned)cx < (unsigned)W_) {
                    p0 = *(const ushort8v*)&src[cx * 16];
                    p1 = *(const ushort8v*)&src[cx * 16 + 8];
                }
                *(ushort8v*)&u.P[ky][r][cgp * 16]     = p0;
                *(ushort8v*)&u.P[ky][r][cgp * 16 + 8] = p1;
            }
        }
    }
    __syncthreads();

    // ---------------- Phase A2: offs = MFMA offset conv ----------------
    {
        floatx4 oa0 = (floatx4){0.f, 0.f, 0.f, 0.f};
        floatx4 oa1 = (floatx4){0.f, 0.f, 0.f, 0.f};
        const int pxt = wslot;
        #pragma unroll
        for (int ky = 0; ky < 3; ++ky) {
            #pragma unroll
            for (int kx = 0; kx < 3; ++kx) {
                const int tap = ky * 3 + kx;
                #pragma unroll
                for (int ks = 0; ks < 2; ++ks) {
                    const int kk = ks * 32 + quad * 8;
                    const short8 af =
                        *(const short8*)&u.P[ky][pxt * 16 + lane15 + kx][kk];
                    const short8 bf0 =
                        *(const short8*)&owtb[(size_t)(tap * 32 + lane15) * 64 + kk];
                    const short8 bf1 =
                        *(const short8*)&owtb[(size_t)(tap * 32 + 16 + lane15) * 64 + kk];
                    oa0 = __builtin_amdgcn_mfma_f32_16x16x32_bf16(af, bf0, oa0, 0, 0, 0);
                    oa1 = __builtin_amdgcn_mfma_f32_16x16x32_bf16(af, bf1, oa1, 0, 0, 0);
                }
            }
        }
        *(floatx4*)&offs[lane15 * 64 + pxt * 16 + quad * 4] = oa0;
        if (lane15 < 2)
            *(floatx4*)&offs[(16 + lane15) * 64 + pxt * 16 + quad * 4] = oa1;
    }
    __syncthreads();

    // ---------------- Phase B: sample (bf16->LDS) + MFMA MAC ----------------
    const int obase = wslot * 16;
    const int cg    = lane & 3;        // 4-channel sub-group within wave's 16 ch
    const int px16  = lane >> 2;       // pixel within px-tile
    floatx4 acc[4];
    #pragma unroll
    for (int t = 0; t < 4; ++t) acc[t] = (floatx4){0.f, 0.f, 0.f, 0.f};
    // wave w samples channels [16w,16w+16): channel group g = wslot in xT
    const unsigned short* xTw = xTb + (size_t)wslot * (HW_ * 16);

    for (int chunk = 0; chunk < 3; ++chunk) {
        // --- B1: sampling. 3 taps x 4 px-tiles; 4 corner b64 loads each ---
        #pragma unroll
        for (int tl = 0; tl < 3; ++tl) {
            const int k  = chunk * 3 + tl;         // global tap 0..8
            const int ky = k / 3, kx = k % 3;
            const float oby = ob[2 * k], obx = ob[2 * k + 1];   // scalar loads
            #pragma unroll
            for (int pxt = 0; pxt < 4; ++pxt) {
                const int px = pxt * 16 + px16;
                const float offy = offs[(2 * k)     * 64 + px] + oby;
                const float offx = offs[(2 * k + 1) * 64 + px] + obx;
                const float py  = (float)(ho - 1 + ky) + offy;
                const float pxx = (float)(wo_base - 1 + kx + px) + offx;
                const float fy = floorf(py), fx = floorf(pxx);
                const int y0 = (int)fy, x0 = (int)fx;
                const int y1 = y0 + 1,  x1 = x0 + 1;
                const float wy1 = py - fy,  wy0 = 1.f - wy1;
                const float wx1 = pxx - fx, wx0 = 1.f - wx1;
                const bool y0v = (unsigned)y0 < (unsigned)H_;
                const bool y1v = (unsigned)y1 < (unsigned)H_;
                const bool x0v = (unsigned)x0 < (unsigned)W_;
                const bool x1v = (unsigned)x1 < (unsigned)W_;
                const float w00 = (y0v && x0v) ? wy0 * wx0 : 0.f;
                const float w01 = (y0v && x1v) ? wy0 * wx1 : 0.f;
                const float w10 = (y1v && x0v) ? wy1 * wx0 : 0.f;
                const float w11 = (y1v && x1v) ? wy1 * wx1 : 0.f;
                const int ry0 = min(max(y0, 0), H_ - 1);
                const int ry1 = min(max(y1, 0), H_ - 1);
                const int cx0 = min(max(x0, 0), W_ - 1);
                const int cx1 = min(max(x1, 0), W_ - 1);
                const int a00 = (ry0 * W_ + cx0) * 16 + cg * 4;
                const int a01 = (ry0 * W_ + cx1) * 16 + cg * 4;
                const int a10 = (ry1 * W_ + cx0) * 16 + cg * 4;
                const int a11 = (ry1 * W_ + cx1) * 16 + cg * 4;
                const ushort4v q00 = *(const ushort4v*)&xTw[a00];
                const ushort4v q01 = *(const ushort4v*)&xTw[a01];
                const ushort4v q10 = *(const ushort4v*)&xTw[a10];
                const ushort4v q11 = *(const ushort4v*)&xTw[a11];
                ushort4v pk;
                #pragma unroll
                for (int q = 0; q < 4; ++q) {
                    const float val = bf2f(q00[q]) * w00 + bf2f(q01[q]) * w01
                                    + bf2f(q10[q]) * w10 + bf2f(q11[q]) * w11;
                    pk[q] = f2bf(val);
                }
                // k_local = tl*64 + wslot*16 + cg*4 ; 16-B chunk low-3 bits
                // XOR-swizzled by px&7 (matches B2 read swizzle)
                const int cidx =
                    tl * 8 + (((wslot << 1) + (cg >> 1)) ^ (px & 7));
                *(ushort4v*)&u.vals[px][cidx * 8 + (cg & 1) * 4] = pk;
            }
        }
        __syncthreads();

        // --- B2: MFMA MAC. 6 k-steps x 4 px-tiles ---
        const unsigned short* wrow =
            wtb + (size_t)(obase + lane15) * 576 + chunk * 192;
        #pragma unroll
        for (int ks = 0; ks < 6; ++ks) {
            const int kk = ks * 32 + quad * 8;
            const short8 bfrag = *(const short8*)(wrow + kk);
            const int ca  = (ks * 4 + quad) >> 3;                    // chunk group
            const int cbr = ((ks * 4 + quad) & 7) ^ (lane15 & 7);    // swizzled
            #pragma unroll
            for (int t = 0; t < 4; ++t) {
                const int row = t * 16 + lane15;
                const short8 afrag =
                    *(const short8*)&u.vals[row][(ca * 8 + cbr) * 8];
                acc[t] = __builtin_amdgcn_mfma_f32_16x16x32_bf16(
                             afrag, bfrag, acc[t], 0, 0, 0);
            }
        }
        __syncthreads();
    }

    // ---------------- Epilogue: stage via LDS, coalesced store ----------------
    #pragma unroll
    for (int t = 0; t < 4; ++t)
        #pragma unroll
        for (int r = 0; r < 4; ++r)
            u.ep[wslot][lane15][t * 16 + quad * 4 + r] = acc[t][r];
    __syncthreads();
    #pragma unroll
    for (int oi = 0; oi < 16; ++oi) {
        const int o = obase + oi;
        out[(size_t)(b * O_ + o) * HW_ + ho * W_ + wo_base + lane] =
            u.ep[wslot][oi][lane] + bias[o];
    }
}

// ---------------------------------------------------------------------------
extern "C" void kernel_launch(void* const* d_in, const int* in_sizes, int n_in,
                              void* d_out, int out_size, void* d_ws, size_t ws_size,
                              hipStream_t stream) {
    const float* x    = (const float*)d_in[0];  // [4,64,128,128]
    const float* ow   = (const float*)d_in[1];  // [18,64,3,3]
    const float* ob   = (const float*)d_in[2];  // [18]
    const float* w    = (const float*)d_in[3];  // [64,64,3,3]
    const float* bias = (const float*)d_in[4];  // [64]
    float* out = (float*)d_out;                 // [4,64,128,128]

    unsigned short* wtb  = (unsigned short*)d_ws;       // [64][576]     73728 B
    unsigned short* owtb = wtb + 576 * O_;              // [9][32][64]   36864 B
    unsigned short* xT   = owtb + 9 * 32 * 64;          // [4][4][128][128][16] 8.4 MB

    repack<<<(576 * O_ + 255) / 256, 256, 0, stream>>>(w, ow, wtb, owtb);
    xpose<<<B_ * H_, 256, 0, stream>>>(x, xT);
    dcn_fused<<<B_ * H_ * (W_ / 64), 256, 0, stream>>>(xT, owtb, ob, wtb, bias, out);
}